// Round 5
// baseline (363.829 us; speedup 1.0000x reference)
//
#include <hip/hip_runtime.h>
#include <hip/hip_fp16.h>
#include <cstddef>

#define HID 64
#define CLS 40

__device__ __forceinline__ float lrelu(float x) { return x >= 0.f ? x : 0.2f * x; }

__device__ __forceinline__ float wmax(float v) {
#pragma unroll
    for (int o = 32; o > 0; o >>= 1) v = fmaxf(v, __shfl_xor(v, o));
    return v;
}
__device__ __forceinline__ float wsum(float v) {
#pragma unroll
    for (int o = 32; o > 0; o >>= 1) v += __shfl_xor(v, o);
    return v;
}

// ---------------- degree init (0; self-loop occupies LAST slot) ----------------
__global__ __launch_bounds__(256) void k_deginit(int* degS, int* degD, int n) {
    int i = blockIdx.x * 256 + threadIdx.x;
    if (i < n) { degS[i] = 0; degD[i] = 0; }
}

// ---------------- GEMM body: 64 rows/block, 4 threads/row ----------------
// Writes Hh (fp16), ds; APPLY=true also writes dssw and dtp={dt, (degD+1)*d3};
// APPLY=false writes raw dtraw/d2raw/d3raw (degrees not final yet).
template <int K, bool APPLY>
__device__ __forceinline__ void gemm_body(const float* __restrict__ X,
                                          const float* __restrict__ W,
                                          const float* __restrict__ aw,
                                          const float* __restrict__ sw,
                                          const int* __restrict__ degS,
                                          const int* __restrict__ degD,
                                          __half* __restrict__ Hh,
                                          float* __restrict__ ds,
                                          float* __restrict__ dssw,
                                          float2* __restrict__ dtp,
                                          float* __restrict__ dtraw,
                                          float* __restrict__ d2raw,
                                          float* __restrict__ d3raw,
                                          int n, int brow, int tid) {
    __shared__ float Wl[HID * K];
    __shared__ float awl[128];
    __shared__ float swl[128];
    for (int i = tid; i < HID * K; i += 256) Wl[i] = W[i];
    if (tid < 128) awl[tid] = aw[tid];
    else swl[tid - 128] = sw[tid - 128];
    __syncthreads();
    int r = brow * 64 + (tid >> 2);
    int seg = tid & 3;
    if (r >= n) return;
    float acc[16];
#pragma unroll
    for (int c = 0; c < 16; c++) acc[c] = 0.f;
    const float* xr = X + (size_t)r * K;
    const float* wb = &Wl[(seg * 16) * K];
    for (int k = 0; k < K; k += 4) {
        float4 xv = *reinterpret_cast<const float4*>(xr + k);
#pragma unroll
        for (int c = 0; c < 16; c++) {
            float4 wv = *reinterpret_cast<const float4*>(wb + c * K + k);
            acc[c] += xv.x * wv.x + xv.y * wv.y + xv.z * wv.z + xv.w * wv.w;
        }
    }
    union { __half h[16]; uint4 u[2]; } hr;
    float d0 = 0.f, d1 = 0.f, d2 = 0.f, d3 = 0.f;
#pragma unroll
    for (int c = 0; c < 16; c++) {
        hr.h[c] = __float2half(acc[c]);
        int cc = seg * 16 + c;
        d0 += acc[c] * awl[cc];
        d1 += acc[c] * awl[64 + cc];
        d2 += acc[c] * swl[cc];
        d3 += acc[c] * swl[64 + cc];
    }
    uint4* hd = reinterpret_cast<uint4*>(Hh + (size_t)r * HID + seg * 16);
    hd[0] = hr.u[0];
    hd[1] = hr.u[1];
    // quad reduce (threads 4q..4q+3 share row r)
    d0 += __shfl_xor(d0, 1); d0 += __shfl_xor(d0, 2);
    d1 += __shfl_xor(d1, 1); d1 += __shfl_xor(d1, 2);
    d2 += __shfl_xor(d2, 1); d2 += __shfl_xor(d2, 2);
    d3 += __shfl_xor(d3, 1); d3 += __shfl_xor(d3, 2);
    if (seg == 0) {
        ds[r] = d0;
        if (APPLY) {
            dssw[r] = (float)(degS[r] + 1) * d2;
            dtp[r] = make_float2(d1, (float)(degD[r] + 1) * d3);
        } else {
            dtraw[r] = d1;
            d2raw[r] = d2;
            d3raw[r] = d3;
        }
    }
}

// ---------------- fused: layer-0 GEMM (independent) + degree count/rank ----------------
__global__ __launch_bounds__(256) void k_fused0(const float* __restrict__ x,
                                                const float* __restrict__ w0,
                                                const float* __restrict__ aw,
                                                const float* __restrict__ sw,
                                                __half* __restrict__ Hh,
                                                float* __restrict__ ds,
                                                float* __restrict__ dtraw,
                                                float* __restrict__ d2raw,
                                                float* __restrict__ d3raw,
                                                const int* __restrict__ ei,
                                                int* degS, int* degD,
                                                unsigned* __restrict__ ranks,
                                                int n, int E, int gb) {
    if ((int)blockIdx.x < gb) {
        gemm_body<128, false>(x, w0, aw, sw, nullptr, nullptr, Hh, ds,
                              nullptr, nullptr, dtraw, d2raw, d3raw,
                              n, blockIdx.x, threadIdx.x);
    } else {
        int t = (blockIdx.x - gb) * 256 + threadIdx.x;
        int stride = (gridDim.x - gb) * 256;
        for (int e = t; e < E; e += stride) {
            int s = ei[e], d = ei[E + e];
            unsigned rs = (unsigned)atomicAdd(&degS[s], 1);
            unsigned rd = (unsigned)atomicAdd(&degD[d], 1);
            ranks[e] = rs | (rd << 16);  // deg < 65536 (random graph, avg 17)
        }
    }
}

// ---------------- layer-1 GEMM ----------------
__global__ __launch_bounds__(256) void k_gemm1(const float* __restrict__ X,
                                               const float* __restrict__ W,
                                               const float* __restrict__ aw,
                                               const float* __restrict__ sw,
                                               const int* __restrict__ degS,
                                               const int* __restrict__ degD,
                                               __half* __restrict__ Hh,
                                               float* __restrict__ ds,
                                               float* __restrict__ dssw,
                                               float2* __restrict__ dtp,
                                               int n) {
    gemm_body<64, true>(X, W, aw, sw, degS, degD, Hh, ds, dssw, dtp,
                        nullptr, nullptr, nullptr, n, blockIdx.x, threadIdx.x);
}

// ---------------- scans (deg+1 for self-loop) ----------------
// scan1S also applies degree scaling to layer-0 raw dots (degs final here).
__global__ __launch_bounds__(1024) void k_scan1S(const int* __restrict__ degS,
                                                 const int* __restrict__ degD,
                                                 const float* __restrict__ d2raw,
                                                 const float* __restrict__ d3raw,
                                                 const float* __restrict__ dtraw,
                                                 int* __restrict__ off,
                                                 int* __restrict__ bsum,
                                                 float* __restrict__ dssw,
                                                 float2* __restrict__ dtp, int n) {
    __shared__ int buf[2][1024];
    int tid = threadIdx.x;
    int i = blockIdx.x * 1024 + tid;
    int v = (i < n) ? degS[i] + 1 : 0;
    int cur = 0;
    buf[0][tid] = v;
    __syncthreads();
#pragma unroll
    for (int o = 1; o < 1024; o <<= 1) {
        int t = buf[cur][tid];
        if (tid >= o) t += buf[cur][tid - o];
        buf[cur ^ 1][tid] = t;
        cur ^= 1;
        __syncthreads();
    }
    if (i < n) {
        off[i] = buf[cur][tid];
        dssw[i] = (float)(degS[i] + 1) * d2raw[i];
        dtp[i] = make_float2(dtraw[i], (float)(degD[i] + 1) * d3raw[i]);
    }
    if (tid == 1023) bsum[blockIdx.x] = buf[cur][1023];
}

__global__ __launch_bounds__(1024) void k_scan1(const int* __restrict__ deg,
                                                int* __restrict__ off,
                                                int* __restrict__ bsum, int n) {
    __shared__ int buf[2][1024];
    int tid = threadIdx.x;
    int i = blockIdx.x * 1024 + tid;
    int v = (i < n) ? deg[i] + 1 : 0;
    int cur = 0;
    buf[0][tid] = v;
    __syncthreads();
#pragma unroll
    for (int o = 1; o < 1024; o <<= 1) {
        int t = buf[cur][tid];
        if (tid >= o) t += buf[cur][tid - o];
        buf[cur ^ 1][tid] = t;
        cur ^= 1;
        __syncthreads();
    }
    if (i < n) off[i] = buf[cur][tid];
    if (tid == 1023) bsum[blockIdx.x] = buf[cur][1023];
}

__global__ void k_scan2(int* bsum, int nb) {
    if (threadIdx.x == 0 && blockIdx.x == 0) {
        int run = 0;
        for (int b = 0; b < nb; b++) { int t = bsum[b]; bsum[b] = run; run += t; }
    }
}

__global__ __launch_bounds__(1024) void k_scan3(const int* __restrict__ deg,
                                                int* __restrict__ off,
                                                const int* __restrict__ bsum,
                                                int n, int total) {
    int i = blockIdx.x * 1024 + threadIdx.x;
    if (i < n) off[i] = off[i] - (deg[i] + 1) + bsum[blockIdx.x];
    if (i == 0) off[n] = total;
}

// ---------------- scatter: XCD-partitioned, atomic-free ----------------
// csrS[slotS] = {dst, norm_bits};  csrD[slotD] = {src, slotS}
// self-loop takes the LAST slot of each segment.
__global__ __launch_bounds__(256) void k_scatter(const int* __restrict__ ei,
                                                 const float* __restrict__ norm,
                                                 const int* __restrict__ offS,
                                                 const int* __restrict__ offD,
                                                 const unsigned* __restrict__ ranks,
                                                 int2* __restrict__ csrS,
                                                 int2* __restrict__ csrD,
                                                 int Et, int E, int N) {
    int grp = blockIdx.x & 7;
    int lo = (int)(((long long)grp * N) / 8);
    int hi = (int)(((long long)(grp + 1) * N) / 8);
    int start = (blockIdx.x >> 3) * 256 + threadIdx.x;
    int stride = (gridDim.x >> 3) * 256;
    for (int e = start; e < Et; e += stride) {
        int s, d, slotS, slotD;
        if (e < E) {
            s = ei[e]; d = ei[E + e];
            unsigned ur = ranks[e];
            slotS = offS[s] + (int)(ur & 0xffffu);
            slotD = offD[d] + (int)(ur >> 16);
        } else {
            s = d = e - E;
            slotS = offS[s + 1] - 1;
            slotD = offD[d + 1] - 1;
        }
        bool doS = (s >= lo) & (s < hi);
        bool doD = (d >= lo) & (d < hi);
        if (doS) csrS[slotS] = make_int2(d, __float_as_int(norm[e]));
        if (doD) csrD[slotD] = make_int2(s, slotS);
    }
}

// ---------------- softmax by src: wave per node ----------------
__global__ __launch_bounds__(256) void k_soft(const int* __restrict__ offS,
                                              const int2* __restrict__ csrS,
                                              const float* __restrict__ ds,
                                              const float* __restrict__ dssw,
                                              const float2* __restrict__ dtp,
                                              const float* __restrict__ ab,
                                              const float* __restrict__ sb,
                                              const float* __restrict__ alpha,
                                              float* __restrict__ w, int n) {
    int node = blockIdx.x * 4 + (threadIdx.x >> 6);
    int lane = threadIdx.x & 63;
    if (node >= n) return;
    int beg = offS[node], end = offS[node + 1];
    int deg = end - beg;
    float ds_s = ds[node], dssw_s = dssw[node];
    float ab0 = ab[0], sb0 = sb[0], al = alpha[0];

    if (deg <= 64) {
        bool valid = lane < deg;
        float sim = -INFINITY, nsim = -INFINITY;
        int pos = beg + lane;
        if (valid) {
            int2 c = csrS[pos];
            float nr = __int_as_float(c.y);
            float2 p = dtp[c.x];
            sim = lrelu(nr * (ds_s + p.x) + ab0);
            nsim = lrelu(dssw_s + p.y + sb0);
        }
        float mAv = wmax(sim), mNv = wmax(nsim);
        float eA = valid ? expf(sim - mAv) : 0.f;
        float eN = valid ? expf(nsim - mNv) : 0.f;
        float sAv = wsum(eA), sNv = wsum(eN);
        if (valid) w[pos] = al * eA / sAv + (1.f - al) * eN / sNv;
    } else {
        float mAv = -INFINITY, mNv = -INFINITY;
        for (int base = 0; base < deg; base += 64) {
            int idx = base + lane;
            float sim = -INFINITY, nsim = -INFINITY;
            if (idx < deg) {
                int2 c = csrS[beg + idx];
                float nr = __int_as_float(c.y);
                float2 p = dtp[c.x];
                sim = lrelu(nr * (ds_s + p.x) + ab0);
                nsim = lrelu(dssw_s + p.y + sb0);
            }
            mAv = fmaxf(mAv, wmax(sim));
            mNv = fmaxf(mNv, wmax(nsim));
        }
        float sAv = 0.f, sNv = 0.f;
        for (int base = 0; base < deg; base += 64) {
            int idx = base + lane;
            float eA = 0.f, eN = 0.f;
            if (idx < deg) {
                int2 c = csrS[beg + idx];
                float nr = __int_as_float(c.y);
                float2 p = dtp[c.x];
                eA = expf(lrelu(nr * (ds_s + p.x) + ab0) - mAv);
                eN = expf(lrelu(dssw_s + p.y + sb0) - mNv);
            }
            sAv += wsum(eA);
            sNv += wsum(eN);
        }
        for (int base = 0; base < deg; base += 64) {
            int idx = base + lane;
            if (idx < deg) {
                int2 c = csrS[beg + idx];
                float nr = __int_as_float(c.y);
                float2 p = dtp[c.x];
                float eA = expf(lrelu(nr * (ds_s + p.x) + ab0) - mAv);
                float eN = expf(lrelu(dssw_s + p.y + sb0) - mNv);
                w[beg + idx] = al * eA / sAv + (1.f - al) * eN / sNv;
            }
        }
    }
}

// ---------------- aggregation by dst: wave per node, 8-way unrolled ----------------
__global__ __launch_bounds__(256) void k_aggr(const int* __restrict__ offD,
                                              const int2* __restrict__ csrD,
                                              const float* __restrict__ w,
                                              const __half* __restrict__ Hh,
                                              const float* __restrict__ bias,
                                              float* __restrict__ out, int n) {
    int node = blockIdx.x * 4 + (threadIdx.x >> 6);
    int lane = threadIdx.x & 63;
    if (node >= n) return;
    int beg = offD[node];
    int deg = offD[node + 1] - beg;
    float m0 = -INFINITY, m1 = -INFINITY, m2 = -INFINITY, m3 = -INFINITY;
    float m4 = -INFINITY, m5 = -INFINITY, m6 = -INFINITY, m7 = -INFINITY;
    for (int base = 0; base < deg; base += 64) {
        int idx = base + lane;
        int s = 0;
        float wv = 0.f;
        if (idx < deg) {
            int2 c = csrD[beg + idx];
            s = c.x;
            wv = w[c.y];
        }
        int cnt = min(64, deg - base);
        int cnt8 = cnt & ~7;
        for (int j = 0; j < cnt8; j += 8) {
            int s0 = __shfl(s, j),     s1 = __shfl(s, j + 1),
                s2 = __shfl(s, j + 2), s3 = __shfl(s, j + 3),
                s4 = __shfl(s, j + 4), s5 = __shfl(s, j + 5),
                s6 = __shfl(s, j + 6), s7 = __shfl(s, j + 7);
            float w0 = __shfl(wv, j),     w1 = __shfl(wv, j + 1),
                  w2 = __shfl(wv, j + 2), w3 = __shfl(wv, j + 3),
                  w4 = __shfl(wv, j + 4), w5 = __shfl(wv, j + 5),
                  w6 = __shfl(wv, j + 6), w7 = __shfl(wv, j + 7);
            float h0 = __half2float(Hh[(size_t)s0 * HID + lane]);
            float h1 = __half2float(Hh[(size_t)s1 * HID + lane]);
            float h2 = __half2float(Hh[(size_t)s2 * HID + lane]);
            float h3 = __half2float(Hh[(size_t)s3 * HID + lane]);
            float h4 = __half2float(Hh[(size_t)s4 * HID + lane]);
            float h5 = __half2float(Hh[(size_t)s5 * HID + lane]);
            float h6 = __half2float(Hh[(size_t)s6 * HID + lane]);
            float h7 = __half2float(Hh[(size_t)s7 * HID + lane]);
            m0 = fmaxf(m0, w0 * h0); m1 = fmaxf(m1, w1 * h1);
            m2 = fmaxf(m2, w2 * h2); m3 = fmaxf(m3, w3 * h3);
            m4 = fmaxf(m4, w4 * h4); m5 = fmaxf(m5, w5 * h5);
            m6 = fmaxf(m6, w6 * h6); m7 = fmaxf(m7, w7 * h7);
        }
        for (int j = cnt8; j < cnt; j++) {
            int sj = __shfl(s, j);
            float wj = __shfl(wv, j);
            m0 = fmaxf(m0, wj * __half2float(Hh[(size_t)sj * HID + lane]));
        }
    }
    float m = fmaxf(fmaxf(fmaxf(m0, m1), fmaxf(m2, m3)),
                    fmaxf(fmaxf(m4, m5), fmaxf(m6, m7)));
    out[(size_t)node * HID + lane] = fmaxf(m + bias[lane], 0.f);
}

// ---------------- logits + log_softmax: 8 lanes/node, 5 classes/lane ----------------
__global__ __launch_bounds__(256) void k_logits(const float* __restrict__ H,
                                                const float* __restrict__ OW,
                                                const float* __restrict__ OB,
                                                float* __restrict__ out, int n) {
    __shared__ float Wl[CLS * HID];
    __shared__ float Bl[CLS];
    int tid = threadIdx.x;
    for (int i = tid; i < CLS * HID; i += 256) Wl[i] = OW[i];
    if (tid < CLS) Bl[tid] = OB[tid];
    __syncthreads();
    int node = blockIdx.x * 32 + (tid >> 3);
    int g = tid & 7;
    if (node >= n) return;
    const float* h = H + (size_t)node * HID;
    float hreg[HID];
#pragma unroll
    for (int k = 0; k < HID; k += 4) {
        float4 hv = *reinterpret_cast<const float4*>(h + k);
        hreg[k] = hv.x; hreg[k + 1] = hv.y; hreg[k + 2] = hv.z; hreg[k + 3] = hv.w;
    }
    float lg[5];
#pragma unroll
    for (int j = 0; j < 5; j++) {
        int c = g * 5 + j;
        float a = 0.f;
        const float* wr = &Wl[c * HID];
#pragma unroll
        for (int k = 0; k < HID; k++) a += hreg[k] * wr[k];
        lg[j] = a + Bl[c];
    }
    float m = lg[0];
#pragma unroll
    for (int j = 1; j < 5; j++) m = fmaxf(m, lg[j]);
    m = fmaxf(m, __shfl_xor(m, 1));
    m = fmaxf(m, __shfl_xor(m, 2));
    m = fmaxf(m, __shfl_xor(m, 4));
    float s = 0.f;
#pragma unroll
    for (int j = 0; j < 5; j++) s += expf(lg[j] - m);
    s += __shfl_xor(s, 1);
    s += __shfl_xor(s, 2);
    s += __shfl_xor(s, 4);
    float lse = m + logf(s);
    float* o = out + (size_t)node * CLS + g * 5;
#pragma unroll
    for (int j = 0; j < 5; j++) o[j] = lg[j] - lse;
}

extern "C" void kernel_launch(void* const* d_in, const int* in_sizes, int n_in,
                              void* d_out, int out_size, void* d_ws, size_t ws_size,
                              hipStream_t stream) {
    const float* x   = (const float*)d_in[0];
    const int*   ei  = (const int*)d_in[1];
    const float* nrm = (const float*)d_in[2];
    const float* w0  = (const float*)d_in[3];
    const float* w1  = (const float*)d_in[4];
    const float* aw0 = (const float*)d_in[5];
    const float* ab0 = (const float*)d_in[6];
    const float* aw1 = (const float*)d_in[7];
    const float* ab1 = (const float*)d_in[8];
    const float* sw0 = (const float*)d_in[9];
    const float* sb0 = (const float*)d_in[10];
    const float* sw1 = (const float*)d_in[11];
    const float* sb1 = (const float*)d_in[12];
    const float* al0 = (const float*)d_in[13];
    const float* al1 = (const float*)d_in[14];
    const float* b0  = (const float*)d_in[15];
    const float* b1  = (const float*)d_in[16];
    const float* ow  = (const float*)d_in[17];
    const float* ob  = (const float*)d_in[18];
    float* out = (float*)d_out;

    int N = in_sizes[0] / 128;
    int E = in_sizes[1] / 2;
    int Et = E + N;

    char* base = (char*)d_ws;
    size_t off = 0;
    auto alloc = [&](size_t bytes) {
        void* p = base + off;
        off += (bytes + 255) & ~(size_t)255;
        return p;
    };
    int* degS = (int*)alloc(N * 4);
    int* degD = (int*)alloc(N * 4);
    int* offS = (int*)alloc((N + 1) * 4);
    int* offD = (int*)alloc((N + 1) * 4);
    int* bsum = (int*)alloc(128 * 4);
    unsigned* ranks = (unsigned*)alloc((size_t)E * 4);
    int2* csrS = (int2*)alloc((size_t)Et * 8);
    int2* csrD = (int2*)alloc((size_t)Et * 8);
    float* wgt   = (float*)alloc((size_t)Et * 4);
    float* ds    = (float*)alloc(N * 4);
    float* dssw  = (float*)alloc(N * 4);
    float* dtraw = (float*)alloc(N * 4);
    float* d2raw = (float*)alloc(N * 4);
    float* d3raw = (float*)alloc(N * 4);
    float2* dtp  = (float2*)alloc((size_t)N * 8);
    __half* Hh   = (__half*)alloc((size_t)N * HID * 2);
    float* lay   = (float*)alloc((size_t)N * HID * 4);

    int nbN = (N + 255) / 256;
    int nbScan = (N + 1023) / 1024;
    int nbW = (N + 3) / 4;
    int gb = (N + 63) / 64;               // gemm blocks (64 rows each)
    int cnb = (E + 1023) / 1024;          // count blocks (~4 edges/thread)

    k_deginit<<<nbN, 256, 0, stream>>>(degS, degD, N);
    k_fused0<<<gb + cnb, 256, 0, stream>>>(x, w0, aw0, sw0, Hh, ds,
                                           dtraw, d2raw, d3raw,
                                           ei, degS, degD, ranks, N, E, gb);
    k_scan1S<<<nbScan, 1024, 0, stream>>>(degS, degD, d2raw, d3raw, dtraw,
                                          offS, bsum, dssw, dtp, N);
    k_scan2<<<1, 64, 0, stream>>>(bsum, nbScan);
    k_scan3<<<nbScan, 1024, 0, stream>>>(degS, offS, bsum, N, Et);
    k_scan1<<<nbScan, 1024, 0, stream>>>(degD, offD, bsum, N);
    k_scan2<<<1, 64, 0, stream>>>(bsum, nbScan);
    k_scan3<<<nbScan, 1024, 0, stream>>>(degD, offD, bsum, N, Et);
    k_scatter<<<2048, 256, 0, stream>>>(ei, nrm, offS, offD, ranks,
                                        csrS, csrD, Et, E, N);

    // layer 0
    k_soft<<<nbW, 256, 0, stream>>>(offS, csrS, ds, dssw, dtp,
                                    ab0, sb0, al0, wgt, N);
    k_aggr<<<nbW, 256, 0, stream>>>(offD, csrD, wgt, Hh, b0, lay, N);

    // layer 1
    k_gemm1<<<gb, 256, 0, stream>>>(lay, w1, aw1, sw1, degS, degD,
                                    Hh, ds, dssw, dtp, N);
    k_soft<<<nbW, 256, 0, stream>>>(offS, csrS, ds, dssw, dtp,
                                    ab1, sb1, al1, wgt, N);
    k_aggr<<<nbW, 256, 0, stream>>>(offD, csrD, wgt, Hh, b1, lay, N);

    k_logits<<<(N + 31) / 32, 256, 0, stream>>>(lay, ow, ob, out, N);
}

// Round 6
// 329.733 us; speedup vs baseline: 1.1034x; 1.1034x over previous
//
#include <hip/hip_runtime.h>
#include <hip/hip_fp16.h>
#include <cstddef>

#define HID 64
#define CLS 40

__device__ __forceinline__ float lrelu(float x) { return x >= 0.f ? x : 0.2f * x; }

__device__ __forceinline__ float wmax(float v) {
#pragma unroll
    for (int o = 32; o > 0; o >>= 1) v = fmaxf(v, __shfl_xor(v, o));
    return v;
}
__device__ __forceinline__ float wsum(float v) {
#pragma unroll
    for (int o = 32; o > 0; o >>= 1) v += __shfl_xor(v, o);
    return v;
}

// ---------------- degree init (0; self-loop occupies LAST slot) ----------------
__global__ __launch_bounds__(256) void k_deginit(int* degS, int* degD, int n) {
    int i = blockIdx.x * 256 + threadIdx.x;
    if (i < n) { degS[i] = 0; degD[i] = 0; }
}

// ---------------- GEMM body: 64 rows/block, 4 threads/row ----------------
// W staged in LDS with row stride K+4 and seg-interleaved columns:
//   seg owns cc = 16*(c>>2) + 4*seg + (c&3), c=0..15.
// Seg-to-seg LDS delta = 4*(K+4)*4B = 64B mod 128 -> 2-way conflict (free),
// float4 loads stay 16B aligned ((K+4)%4==0).
template <int K, bool APPLY>
__device__ __forceinline__ void gemm_body(const float* __restrict__ X,
                                          const float* __restrict__ W,
                                          const float* __restrict__ aw,
                                          const float* __restrict__ sw,
                                          const int* __restrict__ degS,
                                          const int* __restrict__ degD,
                                          __half* __restrict__ Hh,
                                          float* __restrict__ ds,
                                          float* __restrict__ dssw,
                                          float2* __restrict__ dtp,
                                          float* __restrict__ dtraw,
                                          float* __restrict__ d2raw,
                                          float* __restrict__ d3raw,
                                          int n, int brow, int tid) {
    constexpr int STR = K + 4;
    __shared__ float Wl[HID * STR];
    __shared__ float awl[128];
    __shared__ float swl[128];
    for (int i = tid; i < HID * K; i += 256) {
        int c = i / K, k = i % K;  // K pow2 -> shifts
        Wl[c * STR + k] = W[i];
    }
    if (tid < 128) awl[tid] = aw[tid];
    else swl[tid - 128] = sw[tid - 128];
    __syncthreads();
    int r = brow * 64 + (tid >> 2);
    int seg = tid & 3;
    if (r >= n) return;
    float acc[16];
#pragma unroll
    for (int c = 0; c < 16; c++) acc[c] = 0.f;
    const float* xr = X + (size_t)r * K;
    const float* wb = &Wl[4 * seg * STR];
    for (int k = 0; k < K; k += 4) {
        float4 xv = *reinterpret_cast<const float4*>(xr + k);
#pragma unroll
        for (int c = 0; c < 16; c++) {
            int crel = 16 * (c >> 2) + (c & 3);  // + 4*seg folded into wb
            float4 wv = *reinterpret_cast<const float4*>(wb + crel * STR + k);
            acc[c] += xv.x * wv.x + xv.y * wv.y + xv.z * wv.z + xv.w * wv.w;
        }
    }
    float d0 = 0.f, d1 = 0.f, d2 = 0.f, d3 = 0.f;
#pragma unroll
    for (int c = 0; c < 16; c++) {
        int cc = 16 * (c >> 2) + 4 * seg + (c & 3);
        d0 += acc[c] * awl[cc];
        d1 += acc[c] * awl[64 + cc];
        d2 += acc[c] * swl[cc];
        d3 += acc[c] * swl[64 + cc];
    }
#pragma unroll
    for (int t = 0; t < 4; t++) {
        union { __half2 h2[2]; uint2 u; } st;
        st.h2[0] = __floats2half2_rn(acc[4 * t], acc[4 * t + 1]);
        st.h2[1] = __floats2half2_rn(acc[4 * t + 2], acc[4 * t + 3]);
        *reinterpret_cast<uint2*>(Hh + (size_t)r * HID + 16 * t + 4 * seg) = st.u;
    }
    // quad reduce (threads 4q..4q+3 share row r)
    d0 += __shfl_xor(d0, 1); d0 += __shfl_xor(d0, 2);
    d1 += __shfl_xor(d1, 1); d1 += __shfl_xor(d1, 2);
    d2 += __shfl_xor(d2, 1); d2 += __shfl_xor(d2, 2);
    d3 += __shfl_xor(d3, 1); d3 += __shfl_xor(d3, 2);
    if (seg == 0) {
        ds[r] = d0;
        if (APPLY) {
            dssw[r] = (float)(degS[r] + 1) * d2;
            dtp[r] = make_float2(d1, (float)(degD[r] + 1) * d3);
        } else {
            dtraw[r] = d1;
            d2raw[r] = d2;
            d3raw[r] = d3;
        }
    }
}

// ---------------- fused: layer-0 GEMM (independent) + degree count/rank ----------------
__global__ __launch_bounds__(256) void k_fused0(const float* __restrict__ x,
                                                const float* __restrict__ w0,
                                                const float* __restrict__ aw,
                                                const float* __restrict__ sw,
                                                __half* __restrict__ Hh,
                                                float* __restrict__ ds,
                                                float* __restrict__ dtraw,
                                                float* __restrict__ d2raw,
                                                float* __restrict__ d3raw,
                                                const int* __restrict__ ei,
                                                int* degS, int* degD,
                                                unsigned* __restrict__ ranks,
                                                int n, int E, int gb) {
    if ((int)blockIdx.x < gb) {
        gemm_body<128, false>(x, w0, aw, sw, nullptr, nullptr, Hh, ds,
                              nullptr, nullptr, dtraw, d2raw, d3raw,
                              n, blockIdx.x, threadIdx.x);
    } else {
        int t = (blockIdx.x - gb) * 256 + threadIdx.x;
        int stride = (gridDim.x - gb) * 256;
        for (int e = t; e < E; e += stride) {
            int s = ei[e], d = ei[E + e];
            unsigned rs = (unsigned)atomicAdd(&degS[s], 1);
            unsigned rd = (unsigned)atomicAdd(&degD[d], 1);
            ranks[e] = rs | (rd << 16);  // deg < 65536
        }
    }
}

// ---------------- layer-1 GEMM ----------------
__global__ __launch_bounds__(256) void k_gemm1(const float* __restrict__ X,
                                               const float* __restrict__ W,
                                               const float* __restrict__ aw,
                                               const float* __restrict__ sw,
                                               const int* __restrict__ degS,
                                               const int* __restrict__ degD,
                                               __half* __restrict__ Hh,
                                               float* __restrict__ ds,
                                               float* __restrict__ dssw,
                                               float2* __restrict__ dtp,
                                               int n) {
    gemm_body<64, true>(X, W, aw, sw, degS, degD, Hh, ds, dssw, dtp,
                        nullptr, nullptr, nullptr, n, blockIdx.x, threadIdx.x);
}

// ---------------- combined scans: S (blocks 0..nb-1) and D (nb..2nb-1) ----------------
// scanA also applies degree scaling to layer-0 raw dots (degrees final here).
__global__ __launch_bounds__(1024) void k_scanA(const int* __restrict__ degS,
                                                const int* __restrict__ degD,
                                                const float* __restrict__ d2raw,
                                                const float* __restrict__ d3raw,
                                                const float* __restrict__ dtraw,
                                                int* __restrict__ offS,
                                                int* __restrict__ offD,
                                                int* __restrict__ bsum,
                                                float* __restrict__ dssw,
                                                float2* __restrict__ dtp,
                                                int n, int nb) {
    __shared__ int buf[2][1024];
    int which = (int)blockIdx.x >= nb;
    const int* deg = which ? degD : degS;
    int* off = which ? offD : offS;
    int b = blockIdx.x - (which ? nb : 0);
    int tid = threadIdx.x;
    int i = b * 1024 + tid;
    int v = (i < n) ? deg[i] + 1 : 0;
    int cur = 0;
    buf[0][tid] = v;
    __syncthreads();
#pragma unroll
    for (int o = 1; o < 1024; o <<= 1) {
        int t = buf[cur][tid];
        if (tid >= o) t += buf[cur][tid - o];
        buf[cur ^ 1][tid] = t;
        cur ^= 1;
        __syncthreads();
    }
    if (i < n) off[i] = buf[cur][tid];
    if (tid == 1023) bsum[which * 64 + b] = buf[cur][1023];
    if (!which && i < n) {
        dssw[i] = (float)(degS[i] + 1) * d2raw[i];
        dtp[i] = make_float2(dtraw[i], (float)(degD[i] + 1) * d3raw[i]);
    }
}

__global__ void k_scanB(int* bsum, int nb) {
    int t = threadIdx.x;
    if (t < 2) {
        int run = 0;
        for (int b = 0; b < nb; b++) {
            int x = bsum[t * 64 + b];
            bsum[t * 64 + b] = run;
            run += x;
        }
    }
}

__global__ __launch_bounds__(1024) void k_scanC(const int* __restrict__ degS,
                                                const int* __restrict__ degD,
                                                int* __restrict__ offS,
                                                int* __restrict__ offD,
                                                const int* __restrict__ bsum,
                                                int n, int total, int nb) {
    int which = (int)blockIdx.x >= nb;
    const int* deg = which ? degD : degS;
    int* off = which ? offD : offS;
    int b = blockIdx.x - (which ? nb : 0);
    int i = b * 1024 + threadIdx.x;
    if (i < n) off[i] = off[i] - (deg[i] + 1) + bsum[which * 64 + b];
    if (i == 0) off[n] = total;
}

// ---------------- scatter: XCD-partitioned, atomic-free ----------------
// csrS[slotS] = {dst, norm_bits};  csrD[slotD] = {src, slotS}
// self-loop takes the LAST slot of each segment.
__global__ __launch_bounds__(256) void k_scatter(const int* __restrict__ ei,
                                                 const float* __restrict__ norm,
                                                 const int* __restrict__ offS,
                                                 const int* __restrict__ offD,
                                                 const unsigned* __restrict__ ranks,
                                                 int2* __restrict__ csrS,
                                                 int2* __restrict__ csrD,
                                                 int Et, int E, int N) {
    int grp = blockIdx.x & 7;
    int lo = (int)(((long long)grp * N) / 8);
    int hi = (int)(((long long)(grp + 1) * N) / 8);
    int start = (blockIdx.x >> 3) * 256 + threadIdx.x;
    int stride = (gridDim.x >> 3) * 256;
    for (int e = start; e < Et; e += stride) {
        int s, d, slotS, slotD;
        if (e < E) {
            s = ei[e]; d = ei[E + e];
            unsigned ur = ranks[e];
            slotS = offS[s] + (int)(ur & 0xffffu);
            slotD = offD[d] + (int)(ur >> 16);
        } else {
            s = d = e - E;
            slotS = offS[s + 1] - 1;
            slotD = offD[d + 1] - 1;
        }
        bool doS = (s >= lo) & (s < hi);
        bool doD = (d >= lo) & (d < hi);
        if (doS) csrS[slotS] = make_int2(d, __float_as_int(norm[e]));
        if (doD) csrD[slotD] = make_int2(s, slotS);
    }
}

// ---------------- softmax by src: wave per node ----------------
__global__ __launch_bounds__(256) void k_soft(const int* __restrict__ offS,
                                              const int2* __restrict__ csrS,
                                              const float* __restrict__ ds,
                                              const float* __restrict__ dssw,
                                              const float2* __restrict__ dtp,
                                              const float* __restrict__ ab,
                                              const float* __restrict__ sb,
                                              const float* __restrict__ alpha,
                                              float* __restrict__ w, int n) {
    int node = blockIdx.x * 4 + (threadIdx.x >> 6);
    int lane = threadIdx.x & 63;
    if (node >= n) return;
    int beg = offS[node], end = offS[node + 1];
    int deg = end - beg;
    float ds_s = ds[node], dssw_s = dssw[node];
    float ab0 = ab[0], sb0 = sb[0], al = alpha[0];

    if (deg <= 64) {
        bool valid = lane < deg;
        float sim = -INFINITY, nsim = -INFINITY;
        int pos = beg + lane;
        if (valid) {
            int2 c = csrS[pos];
            float nr = __int_as_float(c.y);
            float2 p = dtp[c.x];
            sim = lrelu(nr * (ds_s + p.x) + ab0);
            nsim = lrelu(dssw_s + p.y + sb0);
        }
        float mAv = wmax(sim), mNv = wmax(nsim);
        float eA = valid ? expf(sim - mAv) : 0.f;
        float eN = valid ? expf(nsim - mNv) : 0.f;
        float sAv = wsum(eA), sNv = wsum(eN);
        if (valid) w[pos] = al * eA / sAv + (1.f - al) * eN / sNv;
    } else {
        float mAv = -INFINITY, mNv = -INFINITY;
        for (int base = 0; base < deg; base += 64) {
            int idx = base + lane;
            float sim = -INFINITY, nsim = -INFINITY;
            if (idx < deg) {
                int2 c = csrS[beg + idx];
                float nr = __int_as_float(c.y);
                float2 p = dtp[c.x];
                sim = lrelu(nr * (ds_s + p.x) + ab0);
                nsim = lrelu(dssw_s + p.y + sb0);
            }
            mAv = fmaxf(mAv, wmax(sim));
            mNv = fmaxf(mNv, wmax(nsim));
        }
        float sAv = 0.f, sNv = 0.f;
        for (int base = 0; base < deg; base += 64) {
            int idx = base + lane;
            float eA = 0.f, eN = 0.f;
            if (idx < deg) {
                int2 c = csrS[beg + idx];
                float nr = __int_as_float(c.y);
                float2 p = dtp[c.x];
                eA = expf(lrelu(nr * (ds_s + p.x) + ab0) - mAv);
                eN = expf(lrelu(dssw_s + p.y + sb0) - mNv);
            }
            sAv += wsum(eA);
            sNv += wsum(eN);
        }
        for (int base = 0; base < deg; base += 64) {
            int idx = base + lane;
            if (idx < deg) {
                int2 c = csrS[beg + idx];
                float nr = __int_as_float(c.y);
                float2 p = dtp[c.x];
                float eA = expf(lrelu(nr * (ds_s + p.x) + ab0) - mAv);
                float eN = expf(lrelu(dssw_s + p.y + sb0) - mNv);
                w[beg + idx] = al * eA / sAv + (1.f - al) * eN / sNv;
            }
        }
    }
}

// ---------------- aggregation by dst: wave per node, 8-way unrolled ----------------
__global__ __launch_bounds__(256) void k_aggr(const int* __restrict__ offD,
                                              const int2* __restrict__ csrD,
                                              const float* __restrict__ w,
                                              const __half* __restrict__ Hh,
                                              const float* __restrict__ bias,
                                              float* __restrict__ out, int n) {
    int node = blockIdx.x * 4 + (threadIdx.x >> 6);
    int lane = threadIdx.x & 63;
    if (node >= n) return;
    int beg = offD[node];
    int deg = offD[node + 1] - beg;
    float m0 = -INFINITY, m1 = -INFINITY, m2 = -INFINITY, m3 = -INFINITY;
    float m4 = -INFINITY, m5 = -INFINITY, m6 = -INFINITY, m7 = -INFINITY;
    for (int base = 0; base < deg; base += 64) {
        int idx = base + lane;
        int s = 0;
        float wv = 0.f;
        if (idx < deg) {
            int2 c = csrD[beg + idx];
            s = c.x;
            wv = w[c.y];
        }
        int cnt = min(64, deg - base);
        int cnt8 = cnt & ~7;
        for (int j = 0; j < cnt8; j += 8) {
            int s0 = __shfl(s, j),     s1 = __shfl(s, j + 1),
                s2 = __shfl(s, j + 2), s3 = __shfl(s, j + 3),
                s4 = __shfl(s, j + 4), s5 = __shfl(s, j + 5),
                s6 = __shfl(s, j + 6), s7 = __shfl(s, j + 7);
            float w0 = __shfl(wv, j),     w1 = __shfl(wv, j + 1),
                  w2 = __shfl(wv, j + 2), w3 = __shfl(wv, j + 3),
                  w4 = __shfl(wv, j + 4), w5 = __shfl(wv, j + 5),
                  w6 = __shfl(wv, j + 6), w7 = __shfl(wv, j + 7);
            float h0 = __half2float(Hh[(size_t)s0 * HID + lane]);
            float h1 = __half2float(Hh[(size_t)s1 * HID + lane]);
            float h2 = __half2float(Hh[(size_t)s2 * HID + lane]);
            float h3 = __half2float(Hh[(size_t)s3 * HID + lane]);
            float h4 = __half2float(Hh[(size_t)s4 * HID + lane]);
            float h5 = __half2float(Hh[(size_t)s5 * HID + lane]);
            float h6 = __half2float(Hh[(size_t)s6 * HID + lane]);
            float h7 = __half2float(Hh[(size_t)s7 * HID + lane]);
            m0 = fmaxf(m0, w0 * h0); m1 = fmaxf(m1, w1 * h1);
            m2 = fmaxf(m2, w2 * h2); m3 = fmaxf(m3, w3 * h3);
            m4 = fmaxf(m4, w4 * h4); m5 = fmaxf(m5, w5 * h5);
            m6 = fmaxf(m6, w6 * h6); m7 = fmaxf(m7, w7 * h7);
        }
        for (int j = cnt8; j < cnt; j++) {
            int sj = __shfl(s, j);
            float wj = __shfl(wv, j);
            m0 = fmaxf(m0, wj * __half2float(Hh[(size_t)sj * HID + lane]));
        }
    }
    float m = fmaxf(fmaxf(fmaxf(m0, m1), fmaxf(m2, m3)),
                    fmaxf(fmaxf(m4, m5), fmaxf(m6, m7)));
    out[(size_t)node * HID + lane] = fmaxf(m + bias[lane], 0.f);
}

// ---------------- logits + log_softmax: 8 lanes/node, 5 classes/lane ----------------
__global__ __launch_bounds__(256) void k_logits(const float* __restrict__ H,
                                                const float* __restrict__ OW,
                                                const float* __restrict__ OB,
                                                float* __restrict__ out, int n) {
    __shared__ float Wl[CLS * HID];
    __shared__ float Bl[CLS];
    int tid = threadIdx.x;
    for (int i = tid; i < CLS * HID; i += 256) Wl[i] = OW[i];
    if (tid < CLS) Bl[tid] = OB[tid];
    __syncthreads();
    int node = blockIdx.x * 32 + (tid >> 3);
    int g = tid & 7;
    if (node >= n) return;
    const float* h = H + (size_t)node * HID;
    float hreg[HID];
#pragma unroll
    for (int k = 0; k < HID; k += 4) {
        float4 hv = *reinterpret_cast<const float4*>(h + k);
        hreg[k] = hv.x; hreg[k + 1] = hv.y; hreg[k + 2] = hv.z; hreg[k + 3] = hv.w;
    }
    float lg[5];
#pragma unroll
    for (int j = 0; j < 5; j++) {
        int c = g * 5 + j;
        float a = 0.f;
        const float* wr = &Wl[c * HID];
#pragma unroll
        for (int k = 0; k < HID; k++) a += hreg[k] * wr[k];
        lg[j] = a + Bl[c];
    }
    float m = lg[0];
#pragma unroll
    for (int j = 1; j < 5; j++) m = fmaxf(m, lg[j]);
    m = fmaxf(m, __shfl_xor(m, 1));
    m = fmaxf(m, __shfl_xor(m, 2));
    m = fmaxf(m, __shfl_xor(m, 4));
    float s = 0.f;
#pragma unroll
    for (int j = 0; j < 5; j++) s += expf(lg[j] - m);
    s += __shfl_xor(s, 1);
    s += __shfl_xor(s, 2);
    s += __shfl_xor(s, 4);
    float lse = m + logf(s);
    float* o = out + (size_t)node * CLS + g * 5;
#pragma unroll
    for (int j = 0; j < 5; j++) o[j] = lg[j] - lse;
}

extern "C" void kernel_launch(void* const* d_in, const int* in_sizes, int n_in,
                              void* d_out, int out_size, void* d_ws, size_t ws_size,
                              hipStream_t stream) {
    const float* x   = (const float*)d_in[0];
    const int*   ei  = (const int*)d_in[1];
    const float* nrm = (const float*)d_in[2];
    const float* w0  = (const float*)d_in[3];
    const float* w1  = (const float*)d_in[4];
    const float* aw0 = (const float*)d_in[5];
    const float* ab0 = (const float*)d_in[6];
    const float* aw1 = (const float*)d_in[7];
    const float* ab1 = (const float*)d_in[8];
    const float* sw0 = (const float*)d_in[9];
    const float* sb0 = (const float*)d_in[10];
    const float* sw1 = (const float*)d_in[11];
    const float* sb1 = (const float*)d_in[12];
    const float* al0 = (const float*)d_in[13];
    const float* al1 = (const float*)d_in[14];
    const float* b0  = (const float*)d_in[15];
    const float* b1  = (const float*)d_in[16];
    const float* ow  = (const float*)d_in[17];
    const float* ob  = (const float*)d_in[18];
    float* out = (float*)d_out;

    int N = in_sizes[0] / 128;
    int E = in_sizes[1] / 2;
    int Et = E + N;

    char* base = (char*)d_ws;
    size_t off = 0;
    auto alloc = [&](size_t bytes) {
        void* p = base + off;
        off += (bytes + 255) & ~(size_t)255;
        return p;
    };
    int* degS = (int*)alloc(N * 4);
    int* degD = (int*)alloc(N * 4);
    int* offS = (int*)alloc((N + 1) * 4);
    int* offD = (int*)alloc((N + 1) * 4);
    int* bsum = (int*)alloc(128 * 4);
    unsigned* ranks = (unsigned*)alloc((size_t)E * 4);
    int2* csrS = (int2*)alloc((size_t)Et * 8);
    int2* csrD = (int2*)alloc((size_t)Et * 8);
    float* wgt   = (float*)alloc((size_t)Et * 4);
    float* ds    = (float*)alloc(N * 4);
    float* dssw  = (float*)alloc(N * 4);
    float* dtraw = (float*)alloc(N * 4);
    float* d2raw = (float*)alloc(N * 4);
    float* d3raw = (float*)alloc(N * 4);
    float2* dtp  = (float2*)alloc((size_t)N * 8);
    __half* Hh   = (__half*)alloc((size_t)N * HID * 2);
    float* lay   = (float*)alloc((size_t)N * HID * 4);

    int nbN = (N + 255) / 256;
    int nbScan = (N + 1023) / 1024;
    int nbW = (N + 3) / 4;
    int gb = (N + 63) / 64;               // gemm blocks (64 rows each)
    int cnb = (E + 1023) / 1024;          // count blocks (~4 edges/thread)

    k_deginit<<<nbN, 256, 0, stream>>>(degS, degD, N);
    k_fused0<<<gb + cnb, 256, 0, stream>>>(x, w0, aw0, sw0, Hh, ds,
                                           dtraw, d2raw, d3raw,
                                           ei, degS, degD, ranks, N, E, gb);
    k_scanA<<<2 * nbScan, 1024, 0, stream>>>(degS, degD, d2raw, d3raw, dtraw,
                                             offS, offD, bsum, dssw, dtp,
                                             N, nbScan);
    k_scanB<<<1, 64, 0, stream>>>(bsum, nbScan);
    k_scanC<<<2 * nbScan, 1024, 0, stream>>>(degS, degD, offS, offD, bsum,
                                             N, Et, nbScan);
    k_scatter<<<2048, 256, 0, stream>>>(ei, nrm, offS, offD, ranks,
                                        csrS, csrD, Et, E, N);

    // layer 0
    k_soft<<<nbW, 256, 0, stream>>>(offS, csrS, ds, dssw, dtp,
                                    ab0, sb0, al0, wgt, N);
    k_aggr<<<nbW, 256, 0, stream>>>(offD, csrD, wgt, Hh, b0, lay, N);

    // layer 1
    k_gemm1<<<gb, 256, 0, stream>>>(lay, w1, aw1, sw1, degS, degD,
                                    Hh, ds, dssw, dtp, N);
    k_soft<<<nbW, 256, 0, stream>>>(offS, csrS, ds, dssw, dtp,
                                    ab1, sb1, al1, wgt, N);
    k_aggr<<<nbW, 256, 0, stream>>>(offD, csrD, wgt, Hh, b1, lay, N);

    k_logits<<<(N + 31) / 32, 256, 0, stream>>>(lay, ow, ob, out, N);
}

// Round 7
// 329.064 us; speedup vs baseline: 1.1056x; 1.0020x over previous
//
#include <hip/hip_runtime.h>
#include <hip/hip_fp16.h>
#include <cstddef>

#define HID 64
#define CLS 40

__device__ __forceinline__ float lrelu(float x) { return x >= 0.f ? x : 0.2f * x; }

__device__ __forceinline__ float wmax32(float v) {
#pragma unroll
    for (int o = 16; o > 0; o >>= 1) v = fmaxf(v, __shfl_xor(v, o));
    return v;
}
__device__ __forceinline__ float wsum32(float v) {
#pragma unroll
    for (int o = 16; o > 0; o >>= 1) v += __shfl_xor(v, o);
    return v;
}

// ---------------- degree init (0; self-loop occupies LAST slot) ----------------
__global__ __launch_bounds__(256) void k_deginit(int* degS, int* degD, int n) {
    int i = blockIdx.x * 256 + threadIdx.x;
    if (i < n) { degS[i] = 0; degD[i] = 0; }
}

// ---------------- GEMM body: 64 rows/block, 4 threads/row ----------------
// W staged in LDS, row stride K+4, seg-interleaved columns (2-way conflict = free).
// Writes R replicated copies of the fp16 H row (one per XCD consumer).
template <int K, bool APPLY>
__device__ __forceinline__ void gemm_body(const float* __restrict__ X,
                                          const float* __restrict__ W,
                                          const float* __restrict__ aw,
                                          const float* __restrict__ sw,
                                          const int* __restrict__ degS,
                                          const int* __restrict__ degD,
                                          __half* __restrict__ Hh, size_t hN, int R,
                                          float* __restrict__ ds,
                                          float* __restrict__ dssw,
                                          float2* __restrict__ dtp,
                                          float* __restrict__ dtraw,
                                          float* __restrict__ d2raw,
                                          float* __restrict__ d3raw,
                                          int n, int brow, int tid) {
    constexpr int STR = K + 4;
    __shared__ float Wl[HID * STR];
    __shared__ float awl[128];
    __shared__ float swl[128];
    for (int i = tid; i < HID * K; i += 256) {
        int c = i / K, k = i % K;
        Wl[c * STR + k] = W[i];
    }
    if (tid < 128) awl[tid] = aw[tid];
    else swl[tid - 128] = sw[tid - 128];
    __syncthreads();
    int r = brow * 64 + (tid >> 2);
    int seg = tid & 3;
    if (r >= n) return;
    float acc[16];
#pragma unroll
    for (int c = 0; c < 16; c++) acc[c] = 0.f;
    const float* xr = X + (size_t)r * K;
    const float* wb = &Wl[4 * seg * STR];
    for (int k = 0; k < K; k += 4) {
        float4 xv = *reinterpret_cast<const float4*>(xr + k);
#pragma unroll
        for (int c = 0; c < 16; c++) {
            int crel = 16 * (c >> 2) + (c & 3);
            float4 wv = *reinterpret_cast<const float4*>(wb + crel * STR + k);
            acc[c] += xv.x * wv.x + xv.y * wv.y + xv.z * wv.z + xv.w * wv.w;
        }
    }
    float d0 = 0.f, d1 = 0.f, d2 = 0.f, d3 = 0.f;
#pragma unroll
    for (int c = 0; c < 16; c++) {
        int cc = 16 * (c >> 2) + 4 * seg + (c & 3);
        d0 += acc[c] * awl[cc];
        d1 += acc[c] * awl[64 + cc];
        d2 += acc[c] * swl[cc];
        d3 += acc[c] * swl[64 + cc];
    }
    uint2 stv[4];
#pragma unroll
    for (int t = 0; t < 4; t++) {
        union { __half2 h2[2]; uint2 u; } st;
        st.h2[0] = __floats2half2_rn(acc[4 * t], acc[4 * t + 1]);
        st.h2[1] = __floats2half2_rn(acc[4 * t + 2], acc[4 * t + 3]);
        stv[t] = st.u;
    }
    for (int rep = 0; rep < R; rep++) {
        __half* hb = Hh + (size_t)rep * hN + (size_t)r * HID + 4 * seg;
#pragma unroll
        for (int t = 0; t < 4; t++)
            *reinterpret_cast<uint2*>(hb + 16 * t) = stv[t];
    }
    // quad reduce (threads 4q..4q+3 share row r)
    d0 += __shfl_xor(d0, 1); d0 += __shfl_xor(d0, 2);
    d1 += __shfl_xor(d1, 1); d1 += __shfl_xor(d1, 2);
    d2 += __shfl_xor(d2, 1); d2 += __shfl_xor(d2, 2);
    d3 += __shfl_xor(d3, 1); d3 += __shfl_xor(d3, 2);
    if (seg == 0) {
        ds[r] = d0;
        if (APPLY) {
            dssw[r] = (float)(degS[r] + 1) * d2;
            float2 v = make_float2(d1, (float)(degD[r] + 1) * d3);
            for (int rep = 0; rep < 8; rep++) dtp[(size_t)rep * n + r] = v;
        } else {
            dtraw[r] = d1;
            d2raw[r] = d2;
            d3raw[r] = d3;
        }
    }
}

// ---------------- fused: layer-0 GEMM (independent) + degree count/rank ----------------
__global__ __launch_bounds__(256) void k_fused0(const float* __restrict__ x,
                                                const float* __restrict__ w0,
                                                const float* __restrict__ aw,
                                                const float* __restrict__ sw,
                                                __half* __restrict__ Hh, size_t hN, int R,
                                                float* __restrict__ ds,
                                                float* __restrict__ dtraw,
                                                float* __restrict__ d2raw,
                                                float* __restrict__ d3raw,
                                                const int* __restrict__ ei,
                                                int* degS, int* degD,
                                                unsigned* __restrict__ ranks,
                                                int n, int E, int gb) {
    if ((int)blockIdx.x < gb) {
        gemm_body<128, false>(x, w0, aw, sw, nullptr, nullptr, Hh, hN, R, ds,
                              nullptr, nullptr, dtraw, d2raw, d3raw,
                              n, blockIdx.x, threadIdx.x);
    } else {
        int t = (blockIdx.x - gb) * 256 + threadIdx.x;
        int stride = (gridDim.x - gb) * 256;
        for (int e = t; e < E; e += stride) {
            int s = ei[e], d = ei[E + e];
            unsigned rs = (unsigned)atomicAdd(&degS[s], 1);
            unsigned rd = (unsigned)atomicAdd(&degD[d], 1);
            ranks[e] = rs | (rd << 16);  // deg < 65536
        }
    }
}

// ---------------- layer-1 GEMM ----------------
__global__ __launch_bounds__(256) void k_gemm1(const float* __restrict__ X,
                                               const float* __restrict__ W,
                                               const float* __restrict__ aw,
                                               const float* __restrict__ sw,
                                               const int* __restrict__ degS,
                                               const int* __restrict__ degD,
                                               __half* __restrict__ Hh, size_t hN, int R,
                                               float* __restrict__ ds,
                                               float* __restrict__ dssw,
                                               float2* __restrict__ dtp,
                                               int n) {
    gemm_body<64, true>(X, W, aw, sw, degS, degD, Hh, hN, R, ds, dssw, dtp,
                        nullptr, nullptr, nullptr, n, blockIdx.x, threadIdx.x);
}

// ---------------- combined scans: S (blocks 0..nb-1) and D (nb..2nb-1) ----------------
__global__ __launch_bounds__(1024) void k_scanA(const int* __restrict__ degS,
                                                const int* __restrict__ degD,
                                                const float* __restrict__ d2raw,
                                                const float* __restrict__ d3raw,
                                                const float* __restrict__ dtraw,
                                                int* __restrict__ offS,
                                                int* __restrict__ offD,
                                                int* __restrict__ bsum,
                                                float* __restrict__ dssw,
                                                float2* __restrict__ dtp,
                                                int n, int nb) {
    __shared__ int buf[2][1024];
    int which = (int)blockIdx.x >= nb;
    const int* deg = which ? degD : degS;
    int* off = which ? offD : offS;
    int b = blockIdx.x - (which ? nb : 0);
    int tid = threadIdx.x;
    int i = b * 1024 + tid;
    int v = (i < n) ? deg[i] + 1 : 0;
    int cur = 0;
    buf[0][tid] = v;
    __syncthreads();
#pragma unroll
    for (int o = 1; o < 1024; o <<= 1) {
        int t = buf[cur][tid];
        if (tid >= o) t += buf[cur][tid - o];
        buf[cur ^ 1][tid] = t;
        cur ^= 1;
        __syncthreads();
    }
    if (i < n) off[i] = buf[cur][tid];
    if (tid == 1023) bsum[which * 64 + b] = buf[cur][1023];
    if (!which && i < n) {
        dssw[i] = (float)(degS[i] + 1) * d2raw[i];
        float2 vv = make_float2(dtraw[i], (float)(degD[i] + 1) * d3raw[i]);
        for (int rep = 0; rep < 8; rep++) dtp[(size_t)rep * n + i] = vv;
    }
}

__global__ void k_scanB(int* bsum, int nb) {
    int t = threadIdx.x;
    if (t < 2) {
        int run = 0;
        for (int b = 0; b < nb; b++) {
            int x = bsum[t * 64 + b];
            bsum[t * 64 + b] = run;
            run += x;
        }
    }
}

__global__ __launch_bounds__(1024) void k_scanC(const int* __restrict__ degS,
                                                const int* __restrict__ degD,
                                                int* __restrict__ offS,
                                                int* __restrict__ offD,
                                                const int* __restrict__ bsum,
                                                int n, int total, int nb) {
    int which = (int)blockIdx.x >= nb;
    const int* deg = which ? degD : degS;
    int* off = which ? offD : offS;
    int b = blockIdx.x - (which ? nb : 0);
    int i = b * 1024 + threadIdx.x;
    if (i < n) off[i] = off[i] - (deg[i] + 1) + bsum[which * 64 + b];
    if (i == 0) off[n] = total;
}

// ---------------- scatter: XCD-partitioned, atomic-free ----------------
__global__ __launch_bounds__(256) void k_scatter(const int* __restrict__ ei,
                                                 const float* __restrict__ norm,
                                                 const int* __restrict__ offS,
                                                 const int* __restrict__ offD,
                                                 const unsigned* __restrict__ ranks,
                                                 int2* __restrict__ csrS,
                                                 int2* __restrict__ csrD,
                                                 int Et, int E, int N) {
    int grp = blockIdx.x & 7;
    int lo = (int)(((long long)grp * N) / 8);
    int hi = (int)(((long long)(grp + 1) * N) / 8);
    int start = (blockIdx.x >> 3) * 256 + threadIdx.x;
    int stride = (gridDim.x >> 3) * 256;
    for (int e = start; e < Et; e += stride) {
        int s, d, slotS, slotD;
        if (e < E) {
            s = ei[e]; d = ei[E + e];
            unsigned ur = ranks[e];
            slotS = offS[s] + (int)(ur & 0xffffu);
            slotD = offD[d] + (int)(ur >> 16);
        } else {
            s = d = e - E;
            slotS = offS[s + 1] - 1;
            slotD = offD[d + 1] - 1;
        }
        bool doS = (s >= lo) & (s < hi);
        bool doD = (d >= lo) & (d < hi);
        if (doS) csrS[slotS] = make_int2(d, __float_as_int(norm[e]));
        if (doD) csrD[slotD] = make_int2(s, slotS);
    }
}

// ---------------- softmax by src: 32 lanes/node, 2 nodes/wave ----------------
__global__ __launch_bounds__(256) void k_soft(const int* __restrict__ offS,
                                              const int2* __restrict__ csrS,
                                              const float* __restrict__ ds,
                                              const float* __restrict__ dssw,
                                              const float2* __restrict__ dtp,
                                              const float* __restrict__ ab,
                                              const float* __restrict__ sb,
                                              const float* __restrict__ alpha,
                                              float* __restrict__ w, int n) {
    const float2* dtpc = dtp + (size_t)(blockIdx.x & 7) * n;
    int node = blockIdx.x * 8 + (threadIdx.x >> 5);
    int lane = threadIdx.x & 31;
    if (node >= n) return;
    int beg = offS[node];
    int deg = offS[node + 1] - beg;
    float ds_s = ds[node], dssw_s = dssw[node];
    float ab0 = ab[0], sb0 = sb[0], al = alpha[0];

    if (deg <= 32) {
        bool valid = lane < deg;
        float sim = -INFINITY, nsim = -INFINITY;
        int pos = beg + lane;
        if (valid) {
            int2 c = csrS[pos];
            float nr = __int_as_float(c.y);
            float2 p = dtpc[c.x];
            sim = lrelu(nr * (ds_s + p.x) + ab0);
            nsim = lrelu(dssw_s + p.y + sb0);
        }
        float mAv = wmax32(sim), mNv = wmax32(nsim);
        float eA = valid ? expf(sim - mAv) : 0.f;
        float eN = valid ? expf(nsim - mNv) : 0.f;
        float sAv = wsum32(eA), sNv = wsum32(eN);
        if (valid) w[pos] = al * eA / sAv + (1.f - al) * eN / sNv;
    } else {
        float mAv = -INFINITY, mNv = -INFINITY;
        for (int base = 0; base < deg; base += 32) {
            int idx = base + lane;
            if (idx < deg) {
                int2 c = csrS[beg + idx];
                float nr = __int_as_float(c.y);
                float2 p = dtpc[c.x];
                mAv = fmaxf(mAv, lrelu(nr * (ds_s + p.x) + ab0));
                mNv = fmaxf(mNv, lrelu(dssw_s + p.y + sb0));
            }
        }
        mAv = wmax32(mAv);
        mNv = wmax32(mNv);
        float sAv = 0.f, sNv = 0.f;
        for (int base = 0; base < deg; base += 32) {
            int idx = base + lane;
            if (idx < deg) {
                int2 c = csrS[beg + idx];
                float nr = __int_as_float(c.y);
                float2 p = dtpc[c.x];
                sAv += expf(lrelu(nr * (ds_s + p.x) + ab0) - mAv);
                sNv += expf(lrelu(dssw_s + p.y + sb0) - mNv);
            }
        }
        sAv = wsum32(sAv);
        sNv = wsum32(sNv);
        for (int base = 0; base < deg; base += 32) {
            int idx = base + lane;
            if (idx < deg) {
                int2 c = csrS[beg + idx];
                float nr = __int_as_float(c.y);
                float2 p = dtpc[c.x];
                float eA = expf(lrelu(nr * (ds_s + p.x) + ab0) - mAv);
                float eN = expf(lrelu(dssw_s + p.y + sb0) - mNv);
                w[beg + idx] = al * eA / sAv + (1.f - al) * eN / sNv;
            }
        }
    }
}

// ---------------- aggregation by dst: wave per node, XCD-local H copy ----------------
__global__ __launch_bounds__(256) void k_aggr(const int* __restrict__ offD,
                                              const int2* __restrict__ csrD,
                                              const float* __restrict__ w,
                                              const __half* __restrict__ HhR,
                                              size_t hN, int R,
                                              const float* __restrict__ bias,
                                              float* __restrict__ out, int n) {
    const __half* Hh = HhR + (size_t)(blockIdx.x & (R - 1)) * hN;
    int node = blockIdx.x * 4 + (threadIdx.x >> 6);
    int lane = threadIdx.x & 63;
    if (node >= n) return;
    int beg = offD[node];
    int deg = offD[node + 1] - beg;
    float m0 = -INFINITY, m1 = -INFINITY, m2 = -INFINITY, m3 = -INFINITY;
    float m4 = -INFINITY, m5 = -INFINITY, m6 = -INFINITY, m7 = -INFINITY;
    for (int base = 0; base < deg; base += 64) {
        int idx = base + lane;
        int s = 0;
        float wv = 0.f;
        if (idx < deg) {
            int2 c = csrD[beg + idx];
            s = c.x;
            wv = w[c.y];
        }
        int cnt = min(64, deg - base);
        int cnt8 = cnt & ~7;
        for (int j = 0; j < cnt8; j += 8) {
            int s0 = __shfl(s, j),     s1 = __shfl(s, j + 1),
                s2 = __shfl(s, j + 2), s3 = __shfl(s, j + 3),
                s4 = __shfl(s, j + 4), s5 = __shfl(s, j + 5),
                s6 = __shfl(s, j + 6), s7 = __shfl(s, j + 7);
            float w0 = __shfl(wv, j),     w1 = __shfl(wv, j + 1),
                  w2 = __shfl(wv, j + 2), w3 = __shfl(wv, j + 3),
                  w4 = __shfl(wv, j + 4), w5 = __shfl(wv, j + 5),
                  w6 = __shfl(wv, j + 6), w7 = __shfl(wv, j + 7);
            float h0 = __half2float(Hh[(size_t)s0 * HID + lane]);
            float h1 = __half2float(Hh[(size_t)s1 * HID + lane]);
            float h2 = __half2float(Hh[(size_t)s2 * HID + lane]);
            float h3 = __half2float(Hh[(size_t)s3 * HID + lane]);
            float h4 = __half2float(Hh[(size_t)s4 * HID + lane]);
            float h5 = __half2float(Hh[(size_t)s5 * HID + lane]);
            float h6 = __half2float(Hh[(size_t)s6 * HID + lane]);
            float h7 = __half2float(Hh[(size_t)s7 * HID + lane]);
            m0 = fmaxf(m0, w0 * h0); m1 = fmaxf(m1, w1 * h1);
            m2 = fmaxf(m2, w2 * h2); m3 = fmaxf(m3, w3 * h3);
            m4 = fmaxf(m4, w4 * h4); m5 = fmaxf(m5, w5 * h5);
            m6 = fmaxf(m6, w6 * h6); m7 = fmaxf(m7, w7 * h7);
        }
        for (int j = cnt8; j < cnt; j++) {
            int sj = __shfl(s, j);
            float wj = __shfl(wv, j);
            m0 = fmaxf(m0, wj * __half2float(Hh[(size_t)sj * HID + lane]));
        }
    }
    float m = fmaxf(fmaxf(fmaxf(m0, m1), fmaxf(m2, m3)),
                    fmaxf(fmaxf(m4, m5), fmaxf(m6, m7)));
    out[(size_t)node * HID + lane] = fmaxf(m + bias[lane], 0.f);
}

// ---------------- logits + log_softmax: 8 lanes/node, 5 classes/lane ----------------
__global__ __launch_bounds__(256) void k_logits(const float* __restrict__ H,
                                                const float* __restrict__ OW,
                                                const float* __restrict__ OB,
                                                float* __restrict__ out, int n) {
    __shared__ float Wl[CLS * HID];
    __shared__ float Bl[CLS];
    int tid = threadIdx.x;
    for (int i = tid; i < CLS * HID; i += 256) Wl[i] = OW[i];
    if (tid < CLS) Bl[tid] = OB[tid];
    __syncthreads();
    int node = blockIdx.x * 32 + (tid >> 3);
    int g = tid & 7;
    if (node >= n) return;
    const float* h = H + (size_t)node * HID;
    float hreg[HID];
#pragma unroll
    for (int k = 0; k < HID; k += 4) {
        float4 hv = *reinterpret_cast<const float4*>(h + k);
        hreg[k] = hv.x; hreg[k + 1] = hv.y; hreg[k + 2] = hv.z; hreg[k + 3] = hv.w;
    }
    float lg[5];
#pragma unroll
    for (int j = 0; j < 5; j++) {
        int c = g * 5 + j;
        float a = 0.f;
        const float* wr = &Wl[c * HID];
#pragma unroll
        for (int k = 0; k < HID; k++) a += hreg[k] * wr[k];
        lg[j] = a + Bl[c];
    }
    float m = lg[0];
#pragma unroll
    for (int j = 1; j < 5; j++) m = fmaxf(m, lg[j]);
    m = fmaxf(m, __shfl_xor(m, 1));
    m = fmaxf(m, __shfl_xor(m, 2));
    m = fmaxf(m, __shfl_xor(m, 4));
    float s = 0.f;
#pragma unroll
    for (int j = 0; j < 5; j++) s += expf(lg[j] - m);
    s += __shfl_xor(s, 1);
    s += __shfl_xor(s, 2);
    s += __shfl_xor(s, 4);
    float lse = m + logf(s);
    float* o = out + (size_t)node * CLS + g * 5;
#pragma unroll
    for (int j = 0; j < 5; j++) o[j] = lg[j] - lse;
}

extern "C" void kernel_launch(void* const* d_in, const int* in_sizes, int n_in,
                              void* d_out, int out_size, void* d_ws, size_t ws_size,
                              hipStream_t stream) {
    const float* x   = (const float*)d_in[0];
    const int*   ei  = (const int*)d_in[1];
    const float* nrm = (const float*)d_in[2];
    const float* w0  = (const float*)d_in[3];
    const float* w1  = (const float*)d_in[4];
    const float* aw0 = (const float*)d_in[5];
    const float* ab0 = (const float*)d_in[6];
    const float* aw1 = (const float*)d_in[7];
    const float* ab1 = (const float*)d_in[8];
    const float* sw0 = (const float*)d_in[9];
    const float* sb0 = (const float*)d_in[10];
    const float* sw1 = (const float*)d_in[11];
    const float* sb1 = (const float*)d_in[12];
    const float* al0 = (const float*)d_in[13];
    const float* al1 = (const float*)d_in[14];
    const float* b0  = (const float*)d_in[15];
    const float* b1  = (const float*)d_in[16];
    const float* ow  = (const float*)d_in[17];
    const float* ob  = (const float*)d_in[18];
    float* out = (float*)d_out;

    int N = in_sizes[0] / 128;
    int E = in_sizes[1] / 2;
    int Et = E + N;

    char* base = (char*)d_ws;
    size_t off = 0;
    auto alloc = [&](size_t bytes) {
        void* p = base + off;
        off += (bytes + 255) & ~(size_t)255;
        return p;
    };
    int* degS = (int*)alloc(N * 4);
    int* degD = (int*)alloc(N * 4);
    int* offS = (int*)alloc((N + 1) * 4);
    int* offD = (int*)alloc((N + 1) * 4);
    int* bsum = (int*)alloc(128 * 4);
    unsigned* ranks = (unsigned*)alloc((size_t)E * 4);
    int2* csrS = (int2*)alloc((size_t)Et * 8);
    int2* csrD = (int2*)alloc((size_t)Et * 8);
    float* wgt   = (float*)alloc((size_t)Et * 4);
    float* ds    = (float*)alloc(N * 4);
    float* dssw  = (float*)alloc(N * 4);
    float* dtraw = (float*)alloc(N * 4);
    float* d2raw = (float*)alloc(N * 4);
    float* d3raw = (float*)alloc(N * 4);
    float2* dtp  = (float2*)alloc((size_t)N * 8 * 8);  // 8 copies
    float* lay   = (float*)alloc((size_t)N * HID * 4);

    // H replication factor: as many XCD-local copies as fit (power of 2, <=8)
    size_t hbytes = (size_t)N * HID * 2;
    size_t rem = (off < ws_size) ? ws_size - off : hbytes;
    int R = 1;
    while (R < 8 && (size_t)(R * 2) * hbytes <= rem) R <<= 1;
    __half* HhR = (__half*)alloc(hbytes * R);
    size_t hN = (size_t)N * HID;

    int nbN = (N + 255) / 256;
    int nbScan = (N + 1023) / 1024;
    int nbW = (N + 3) / 4;      // aggr: wave per node
    int nbS = (N + 7) / 8;      // soft: 2 nodes per wave
    int gb = (N + 63) / 64;     // gemm blocks (64 rows each)
    int cnb = (E + 1023) / 1024;

    k_deginit<<<nbN, 256, 0, stream>>>(degS, degD, N);
    k_fused0<<<gb + cnb, 256, 0, stream>>>(x, w0, aw0, sw0, HhR, hN, R, ds,
                                           dtraw, d2raw, d3raw,
                                           ei, degS, degD, ranks, N, E, gb);
    k_scanA<<<2 * nbScan, 1024, 0, stream>>>(degS, degD, d2raw, d3raw, dtraw,
                                             offS, offD, bsum, dssw, dtp,
                                             N, nbScan);
    k_scanB<<<1, 64, 0, stream>>>(bsum, nbScan);
    k_scanC<<<2 * nbScan, 1024, 0, stream>>>(degS, degD, offS, offD, bsum,
                                             N, Et, nbScan);
    k_scatter<<<2048, 256, 0, stream>>>(ei, nrm, offS, offD, ranks,
                                        csrS, csrD, Et, E, N);

    // layer 0
    k_soft<<<nbS, 256, 0, stream>>>(offS, csrS, ds, dssw, dtp,
                                    ab0, sb0, al0, wgt, N);
    k_aggr<<<nbW, 256, 0, stream>>>(offD, csrD, wgt, HhR, hN, R, b0, lay, N);

    // layer 1
    k_gemm1<<<gb, 256, 0, stream>>>(lay, w1, aw1, sw1, degS, degD,
                                    HhR, hN, R, ds, dssw, dtp, N);
    k_soft<<<nbS, 256, 0, stream>>>(offS, csrS, ds, dssw, dtp,
                                    ab1, sb1, al1, wgt, N);
    k_aggr<<<nbW, 256, 0, stream>>>(offD, csrD, wgt, HhR, hN, R, b1, lay, N);

    k_logits<<<(N + 31) / 32, 256, 0, stream>>>(lay, ow, ob, out, N);
}